// Round 13
// baseline (78.587 us; speedup 1.0000x reference)
//
#include <hip/hip_runtime.h>
#include <hip/hip_bf16.h>
#include <stdint.h>
#include <math.h>

// STFT power spectrogram via radix-2 decimated INT8 MFMA GEMM with a
// persistent LDS sample-stream (B staged ONCE per block; frames read as
// overlapping views). X(f) = E(f') + e^{-i pi f/512} O(f'), S = |X|^2.
// E/O = 512-pt windowed DFTs of even/odd samples. M=1024 A-rows (E,O re/im
// interleaved), K=512. Zero rows repurposed for E(256)/O(256) -> f=256,512
// free. mfma_i32_32x32x32_i8 exact; SLOTM A-swizzle (0-conflict, R10);
// stream chunk-XOR swizzle q^((q>>3)&7) (involution, 8-lane-distinct).
// R13 fix vs R12: stream tail staged FULL-WAVE (tid<64, uniform branch) --
// partial-exec global_load_lds has unverified HW semantics and was the
// prime suspect for R12's corruption (chunks 1024+ feeding frames 124-127).

#define NFFT     1024
#define NFREQ    513
#define BATCH    32
#define SAMPLES  480000
#define SAMPH    240000                // per-batch half-stream samples
#define HOPH     128                   // hop in half-stream
#define NFRAMES  1872
#define BN       128                   // frames per block
#define NBPB     15                    // n-blocks per batch (15*128 >= 1872)
#define MBLKS    4                     // 128 A-rows each (512 E + 512 O total)
#define KTILES   16                    // 8 E + 8 O, 64-wide
#define NWG      (BATCH * NBPB * MBLKS)   // 1920 = 8 * 240

#define XH_BYTES  ((size_t)BATCH * SAMPLES)              // xe+xo total
#define AWS_BYTES ((size_t)MBLKS * KTILES * 128 * 64)    // 524,288

#define XMAX   6.5f
#define SCALE_X (127.0f / XMAX)
#define DEQ    (XMAX / 16129.0f)
#define DEQ2   (DEQ * DEQ)

// fused prep grid layout
#define QX_BLOCKS 1875
#define BA_BLOCKS 2048                 // AWS_BYTES / 256
#define PREP_BLOCKS (QX_BLOCKS + BA_BLOCKS)

typedef __attribute__((ext_vector_type(4)))  int i32x4;
typedef __attribute__((ext_vector_type(16))) int i32x16;

#define SLOTM(r) ((((r) >> 1) & 3) ^ (((r) >> 3) & 1))

// ---------------- fused prep: quant+deinterleave | build_A ----------------
__global__ __launch_bounds__(256) void k_prep(const float* __restrict__ x,
                                              const float* __restrict__ narr,
                                              const float* __restrict__ w,
                                              const float* __restrict__ window,
                                              signed char* __restrict__ xe,
                                              signed char* __restrict__ xo,
                                              signed char* __restrict__ Aws) {
  const int bid = blockIdx.x;
  const int tid = threadIdx.x;
  if (bid < QX_BLOCKS) {
    size_t i = (size_t)bid * 256 + tid;
    const float4* x4 = (const float4*)x;
    union { signed char c[16]; uint4 v; } pe, po;
    #pragma unroll
    for (int j = 0; j < 8; ++j) {
      float4 a = x4[i * 8 + j];
      float qe  = fminf(127.f, fmaxf(-127.f, a.x * SCALE_X));
      float qo  = fminf(127.f, fmaxf(-127.f, a.y * SCALE_X));
      float qe2 = fminf(127.f, fmaxf(-127.f, a.z * SCALE_X));
      float qo2 = fminf(127.f, fmaxf(-127.f, a.w * SCALE_X));
      pe.c[j * 2]     = (signed char)__float2int_rn(qe);
      po.c[j * 2]     = (signed char)__float2int_rn(qo);
      pe.c[j * 2 + 1] = (signed char)__float2int_rn(qe2);
      po.c[j * 2 + 1] = (signed char)__float2int_rn(qo2);
    }
    ((uint4*)xe)[i] = pe.v;
    ((uint4*)xo)[i] = po.v;
  } else {
    // A i8 [mblk][kt][r 0..127][slot 0..3][16]; kt<8 E (win[2j]), kt>=8 O.
    // er = mblk*128+r: even -> cos f'=er/2; odd -> -sin; er==1 -> real f'=256.
    uint32_t E = (uint32_t)(bid - QX_BLOCKS) * 256 + tid;
    uint32_t e    = E & 15;
    uint32_t s    = (E >> 4) & 3;
    uint32_t r    = (E >> 6) & 127;
    uint32_t kt   = (E >> 13) & 15;
    uint32_t mblk = E >> 17;
    uint32_t er = mblk * 128 + r;
    uint32_t j  = (kt & 7) * 64 + ((s ^ SLOTM(r)) << 4) + e;   // 0..511
    uint32_t odd = (kt >> 3) & 1;
    uint32_t widx = (er == 1) ? 512u : (er & ~1u);
    float ang = w[widx] * narr[j];
    float sn, cs;
    sincosf(ang, &sn, &cs);
    float base = ((er & 1) && (er != 1)) ? -sn : cs;
    float val = 127.f * window[2 * j + odd] * base;
    Aws[E] = (signed char)__float2int_rn(val);
  }
}

// ---------------- main GEMM ----------------
#define GL2LDS(g, l) __builtin_amdgcn_global_load_lds( \
    (const __attribute__((address_space(1))) uint32_t*)(g), \
    (__attribute__((address_space(3))) uint32_t*)(l), 16, 0, 0)

#define WAITV2_BAR() asm volatile("s_waitcnt vmcnt(2)\ns_barrier" ::: "memory")
#define WAIT0_BAR()  asm volatile("s_waitcnt vmcnt(0)\ns_barrier" ::: "memory")
#define LGKM0_BAR()  asm volatile("s_waitcnt lgkmcnt(0)\ns_barrier" ::: "memory")

// LDS: xe stream @0 (17408 B = 1088 chunks), xo @17408, A ring @34816
// (4 slots x 8192). Total 67584 B -> 2 blocks/CU (LDS-wise).
#define SE 0
#define SO 17408
#define AR 34816

// stream swizzle g(q) = q ^ ((q>>3)&7): involution (bits 0-2 from bits >=3);
// read chunks cp = fl*8 + c0 -> 8 consecutive fl hit 8 distinct bank-columns.
// Tail (chunks 1024..1087) staged by ALL 64 lanes of wave 0 (uniform branch).
#define STAGE_STREAM(src, bl) do {                                              \
  _Pragma("unroll") for (int p_ = 0; p_ < 2; ++p_) {                            \
    int q_ = p_ * 512 + tid;                                                    \
    GL2LDS((src) + ((q_ ^ ((q_ >> 3) & 7)) << 4), &lds[(bl) + q_ * 16]);        \
  }                                                                             \
  if (tid < 64) {                                                               \
    int q_ = 1024 + tid;                                                        \
    GL2LDS((src) + ((q_ ^ ((q_ >> 3) & 7)) << 4), &lds[(bl) + q_ * 16]);        \
  }                                                                             \
} while (0)

#define STAGE_A(kt) GL2LDS(Aws + (((size_t)mblk * KTILES + (kt)) * 512 + tid) * 16, \
                           &lds[AR + ((kt) & 3) * 8192 + tid * 16])

#define READ_A2(dst, kt)                                                        \
  _Pragma("unroll") for (int mt_ = 0; mt_ < 2; ++mt_)                           \
  _Pragma("unroll") for (int ks_ = 0; ks_ < 2; ++ks_) {                         \
    int r_ = wr * 64 + mt_ * 32 + lr;                                           \
    int sl_ = (ks_ * 2 + hi) ^ SLOTM(r_);                                       \
    dst[mt_][ks_] = *(const i32x4*)&lds[AR + ((kt) & 3) * 8192 + (r_ * 4 + sl_) * 16]; \
  }

#define READ_B2(dst, ktm7, SB)                                                  \
  _Pragma("unroll") for (int ks_ = 0; ks_ < 2; ++ks_) {                         \
    int cp_ = fl * 8 + (ktm7) * 4 + 2 * ks_ + hi;                               \
    dst[ks_] = *(const i32x4*)&lds[(SB) + ((cp_ ^ ((cp_ >> 3) & 7)) << 4)];     \
  }

#define MFMA2(ACC, A_, B_) do {                                                 \
  __builtin_amdgcn_s_setprio(1);                                                \
  _Pragma("unroll") for (int ks_ = 0; ks_ < 2; ++ks_)                           \
  _Pragma("unroll") for (int mt_ = 0; mt_ < 2; ++mt_)                           \
    ACC[mt_] = __builtin_amdgcn_mfma_i32_32x32x32_i8(                           \
        A_[mt_][ks_], B_[ks_], ACC[mt_], 0, 0, 0);                              \
  __builtin_amdgcn_s_setprio(0);                                                \
  } while (0)

// One iter = 2 K-tiles. vmcnt(2): A(2i),A(2i+1) landed (2 newest may fly).
// lgkmcnt(0)+BAR before stages: all waves' ds_reads complete -> WAR-safe
// to overwrite ring slots (2i)&3,(2i+1)&3 with A(2i+4),A(2i+5).
#define ITER(i, ACC, SB) do {                                                   \
    if ((i) == 7) WAIT0_BAR(); else WAITV2_BAR();                               \
    i32x4 a0[2][2], a1[2][2], b0[2], b1[2];                                     \
    READ_A2(a0, 2 * (i));     READ_B2(b0, (2 * (i)) & 7, SB);                   \
    READ_A2(a1, 2 * (i) + 1); READ_B2(b1, (2 * (i) + 1) & 7, SB);               \
    MFMA2(ACC, a0, b0);                                                         \
    MFMA2(ACC, a1, b1);                                                         \
    LGKM0_BAR();                                                                \
    if ((i) < 6) { STAGE_A(2 * (i) + 4); STAGE_A(2 * (i) + 5); }                \
  } while (0)

__global__ __launch_bounds__(512, 4) void k_stft(const signed char* __restrict__ xe,
                                                 const signed char* __restrict__ xo,
                                                 const signed char* __restrict__ Aws,
                                                 float* __restrict__ out) {
  __shared__ __align__(16) signed char lds[67584];
  const int tid  = threadIdx.x;
  const int lane = tid & 63;
  const int wid  = tid >> 6;
  const int wr = wid >> 2;      // 0..1  (64 A-rows each)
  const int wc = wid & 3;       // 0..3  (32 frames each)
  const int lr = lane & 31;
  const int hi = lane >> 5;
  const int fl = wc * 32 + lr;  // frame within block, 0..127

  // XCD-bijective swizzle: 1920 = 8*240; mblk fastest.
  const int bx = blockIdx.x;
  const int v = (bx & 7) * 240 + (bx >> 3);
  const int mblk = v & 3;
  const int nb = v >> 2;        // 0..479
  const int b  = nb / NBPB;
  const int f0 = (nb - b * NBPB) * BN;   // first frame of block (may pad >1872)

  const signed char* se_src = xe + (size_t)b * SAMPH + (size_t)f0 * HOPH;
  const signed char* so_src = xo + (size_t)b * SAMPH + (size_t)f0 * HOPH;

  i32x16 accE[2], accO[2];
  #pragma unroll
  for (int i = 0; i < 2; ++i)
    #pragma unroll
    for (int e = 0; e < 16; ++e) { accE[i][e] = 0; accO[i][e] = 0; }

  // prologue: both streams (once) + A(0..3); drain all, publish.
  STAGE_STREAM(se_src, SE);
  STAGE_STREAM(so_src, SO);
  STAGE_A(0); STAGE_A(1); STAGE_A(2); STAGE_A(3);
  WAIT0_BAR();

  ITER(0, accE, SE); ITER(1, accE, SE); ITER(2, accE, SE); ITER(3, accE, SE);
  ITER(4, accO, SO); ITER(5, accO, SO); ITER(6, accO, SO); ITER(7, accO, SO);

  // ---- epilogue: in-register radix-2 combine ----
  // C/D: col = lane&31, row = (reg&3)+8*(reg>>2)+4*hi.
  // f' = fbase + mt*16 + aa*4 + 2*hi + q; T=cos-i sin(pi f'/512); P=T*O;
  // S[f'] = DEQ2|E+P|^2, S[512-f'] = DEQ2|E-P|^2. f'==0 regs hold E/O(256).
  const int fbase = mblk * 64 + wr * 32;
  const int tfi = f0 + fl;               // frame index within batch
  if (tfi < NFRAMES) {
    float* op = out + (size_t)b * ((size_t)NFREQ * NFRAMES) + tfi;
    #pragma unroll
    for (int mt = 0; mt < 2; ++mt) {
      i32x16 vE = accE[mt];
      i32x16 vO = accO[mt];
      #pragma unroll
      for (int aa = 0; aa < 4; ++aa)
        #pragma unroll
        for (int q = 0; q < 2; ++q) {
          const int fq = fbase + mt * 16 + aa * 4 + 2 * hi + q;
          float Ere = (float)vE[aa * 4 + 2 * q];
          float Eim = (float)vE[aa * 4 + 2 * q + 1];
          float Ore = (float)vO[aa * 4 + 2 * q];
          float Oim = (float)vO[aa * 4 + 2 * q + 1];
          if (fq == 0) {
            float sp = Ere + Ore, sm = Ere - Ore;
            op[0]                     = DEQ2 * sp * sp;
            op[(size_t)512 * NFRAMES] = DEQ2 * sm * sm;
            op[(size_t)256 * NFRAMES] = DEQ2 * (Eim * Eim + Oim * Oim);
          } else {
            float st, ct;
            sincosf((float)fq * (float)(M_PI / 512.0), &st, &ct);
            float Pre = ct * Ore + st * Oim;
            float Pim = ct * Oim - st * Ore;
            float ar = Ere + Pre, ai = Eim + Pim;
            float br = Ere - Pre, bi = Eim - Pim;
            op[(size_t)fq * NFRAMES]         = DEQ2 * (ar * ar + ai * ai);
            op[(size_t)(512 - fq) * NFRAMES] = DEQ2 * (br * br + bi * bi);
          }
        }
    }
  }
}

extern "C" void kernel_launch(void* const* d_in, const int* in_sizes, int n_in,
                              void* d_out, int out_size, void* d_ws, size_t ws_size,
                              hipStream_t stream) {
  const float* x      = (const float*)d_in[0];
  const float* narr   = (const float*)d_in[1];
  const float* w      = (const float*)d_in[2];
  const float* window = (const float*)d_in[3];
  float* out = (float*)d_out;

  signed char* xe  = (signed char*)d_ws;
  signed char* xo  = xe + (size_t)BATCH * SAMPH;
  signed char* Aws = xo + (size_t)BATCH * SAMPH;
  if (ws_size < XH_BYTES + AWS_BYTES) return;  // 15.9 MB

  k_prep<<<PREP_BLOCKS, 256, 0, stream>>>(x, narr, w, window, xe, xo, Aws);
  k_stft<<<NWG, 512, 0, stream>>>(xe, xo, Aws, out);
}

// Round 14
// 64.168 us; speedup vs baseline: 1.2247x; 1.2247x over previous
//
#include <hip/hip_runtime.h>
#include <hip/hip_bf16.h>
#include <stdint.h>
#include <math.h>

// STFT power spectrogram via radix-2 decimated INT8 MFMA GEMM with a
// persistent LDS sample-stream. X(f) = E(f') + e^{-i pi f/512} O(f'),
// S = |X|^2. E/O = 512-pt windowed DFTs of even/odd samples.
// R14 vs R13: 256-thread blocks (4 waves 2x2, wave-tile 64x64) -> read:MFMA
// ratio 1.0 and 2 blocks/CU overlap; stream swizzle gains bit-3/6 term
// (R13's 1.97M conflicts = lanes 8 apart colliding); epilogue sincosf ->
// twiddle table. A-layout/SLOTM/quant identical to R13 (proven).

#define NFFT     1024
#define NFREQ    513
#define BATCH    32
#define SAMPLES  480000
#define SAMPH    240000                // per-batch half-stream samples
#define HOPH     128                   // hop in half-stream
#define NFRAMES  1872
#define BN       128                   // frames per block
#define NBPB     15                    // 15*128 >= 1872
#define MBLKS    4                     // 128 E-rows (+128 O) per block
#define KTILES   16                    // 8 E + 8 O, 64-wide
#define NWG      (BATCH * NBPB * MBLKS)   // 1920 = 8 * 240

#define XH_BYTES  ((size_t)BATCH * SAMPLES)              // xe+xo total
#define AWS_BYTES ((size_t)MBLKS * KTILES * 128 * 64)    // 524,288
#define TW_BYTES  (513 * 8)

#define XMAX   6.5f
#define SCALE_X (127.0f / XMAX)
#define DEQ    (XMAX / 16129.0f)
#define DEQ2   (DEQ * DEQ)

#define QX_BLOCKS 1875
#define BA_BLOCKS 2048
#define PREP_BLOCKS (QX_BLOCKS + BA_BLOCKS + 1)

typedef __attribute__((ext_vector_type(4)))  int i32x4;
typedef __attribute__((ext_vector_type(16))) int i32x16;

#define SLOTM(r) ((((r) >> 1) & 3) ^ (((r) >> 3) & 1))
// Stream chunk swizzle: involution (mask from bits>=3 only, XOR hits bits<3).
// Read cp = fl*8 + K (K lane-uniform): col = (K&7) ^ ((u ^ (u>>3)) & 7) with
// u = fl + (K>>3): 8 consecutive lanes -> 8 distinct cols; lanes 8 apart ->
// u>>3 differs -> distinct. Kills R13's 4-way collision.
#define SWZ(q) ((q) ^ ((((q) >> 3) ^ ((q) >> 6)) & 7))

// ---------------- fused prep: quant+deinterleave | build_A | twiddle ------
__global__ __launch_bounds__(256) void k_prep(const float* __restrict__ x,
                                              const float* __restrict__ narr,
                                              const float* __restrict__ w,
                                              const float* __restrict__ window,
                                              signed char* __restrict__ xe,
                                              signed char* __restrict__ xo,
                                              signed char* __restrict__ Aws,
                                              float2* __restrict__ tw) {
  const int bid = blockIdx.x;
  const int tid = threadIdx.x;
  if (bid < QX_BLOCKS) {
    size_t i = (size_t)bid * 256 + tid;
    const float4* x4 = (const float4*)x;
    union { signed char c[16]; uint4 v; } pe, po;
    #pragma unroll
    for (int j = 0; j < 8; ++j) {
      float4 a = x4[i * 8 + j];
      float qe  = fminf(127.f, fmaxf(-127.f, a.x * SCALE_X));
      float qo  = fminf(127.f, fmaxf(-127.f, a.y * SCALE_X));
      float qe2 = fminf(127.f, fmaxf(-127.f, a.z * SCALE_X));
      float qo2 = fminf(127.f, fmaxf(-127.f, a.w * SCALE_X));
      pe.c[j * 2]     = (signed char)__float2int_rn(qe);
      po.c[j * 2]     = (signed char)__float2int_rn(qo);
      pe.c[j * 2 + 1] = (signed char)__float2int_rn(qe2);
      po.c[j * 2 + 1] = (signed char)__float2int_rn(qo2);
    }
    ((uint4*)xe)[i] = pe.v;
    ((uint4*)xo)[i] = po.v;
  } else if (bid < QX_BLOCKS + BA_BLOCKS) {
    // A i8 [mblk][kt][r 0..127][slot 0..3][16]; kt<8 E (win[2j]), kt>=8 O.
    uint32_t E = (uint32_t)(bid - QX_BLOCKS) * 256 + tid;
    uint32_t e    = E & 15;
    uint32_t s    = (E >> 4) & 3;
    uint32_t r    = (E >> 6) & 127;
    uint32_t kt   = (E >> 13) & 15;
    uint32_t mblk = E >> 17;
    uint32_t er = mblk * 128 + r;
    uint32_t j  = (kt & 7) * 64 + ((s ^ SLOTM(r)) << 4) + e;   // 0..511
    uint32_t odd = (kt >> 3) & 1;
    uint32_t widx = (er == 1) ? 512u : (er & ~1u);
    float ang = w[widx] * narr[j];
    float sn, cs;
    sincosf(ang, &sn, &cs);
    float base = ((er & 1) && (er != 1)) ? -sn : cs;
    float val = 127.f * window[2 * j + odd] * base;
    Aws[E] = (signed char)__float2int_rn(val);
  } else {
    for (int j = tid; j <= 512; j += 256) {
      float st, ct;
      sincosf((float)j * (float)(M_PI / 512.0), &st, &ct);
      tw[j] = make_float2(ct, st);
    }
  }
}

// ---------------- main GEMM ----------------
#define GL2LDS(g, l) __builtin_amdgcn_global_load_lds( \
    (const __attribute__((address_space(1))) uint32_t*)(g), \
    (__attribute__((address_space(3))) uint32_t*)(l), 16, 0, 0)

#define WAITV4_BAR() asm volatile("s_waitcnt vmcnt(4)\ns_barrier" ::: "memory")
#define WAIT0_BAR()  asm volatile("s_waitcnt vmcnt(0)\ns_barrier" ::: "memory")
#define LGKM0_BAR()  asm volatile("s_waitcnt lgkmcnt(0)\ns_barrier" ::: "memory")

// LDS: xe stream @0 (17408 B = 1088 chunks), xo @17408, A ring @34816
// (4 slots x 8192). Total 67584 -> 2 blocks/CU.
#define SE 0
#define SO 17408
#define AR 34816

// 256 threads: 4 full chunks each + tail by wave 0 (full-wave, R13 lesson).
#define STAGE_STREAM(src, bl) do {                                              \
  _Pragma("unroll") for (int p_ = 0; p_ < 4; ++p_) {                            \
    int q_ = p_ * 256 + tid;                                                    \
    GL2LDS((src) + (SWZ(q_) << 4), &lds[(bl) + q_ * 16]);                       \
  }                                                                             \
  if (tid < 64) {                                                               \
    int q_ = 1024 + tid;                                                        \
    GL2LDS((src) + (SWZ(q_) << 4), &lds[(bl) + q_ * 16]);                       \
  }                                                                             \
} while (0)

// A tile = 8 KB = 512 chunks -> 2 per thread (2 vmcnt items per STAGE_A).
#define STAGE_A(kt) do {                                                        \
  _Pragma("unroll") for (int j_ = 0; j_ < 2; ++j_) {                            \
    int ci_ = j_ * 256 + tid;                                                   \
    GL2LDS(Aws + (((size_t)mblk * KTILES + (kt)) * 512 + ci_) * 16,             \
           &lds[AR + ((kt) & 3) * 8192 + ci_ * 16]);                            \
  } } while (0)

#define READ_A2(dst, kt)                                                        \
  _Pragma("unroll") for (int mt_ = 0; mt_ < 2; ++mt_)                           \
  _Pragma("unroll") for (int ks_ = 0; ks_ < 2; ++ks_) {                         \
    int r_ = wr * 64 + mt_ * 32 + lr;                                           \
    int sl_ = (ks_ * 2 + hi) ^ SLOTM(r_);                                       \
    dst[mt_][ks_] = *(const i32x4*)&lds[AR + ((kt) & 3) * 8192 + (r_ * 4 + sl_) * 16]; \
  }

#define READ_B2(dst, ktm7, SB)                                                  \
  _Pragma("unroll") for (int nt_ = 0; nt_ < 2; ++nt_)                           \
  _Pragma("unroll") for (int ks_ = 0; ks_ < 2; ++ks_) {                         \
    int cp_ = (wc * 64 + nt_ * 32 + lr) * 8 + (ktm7) * 4 + 2 * ks_ + hi;        \
    dst[nt_][ks_] = *(const i32x4*)&lds[(SB) + (SWZ(cp_) << 4)];                \
  }

#define MFMA8(ACC, A_, B_) do {                                                 \
  __builtin_amdgcn_s_setprio(1);                                                \
  _Pragma("unroll") for (int ks_ = 0; ks_ < 2; ++ks_)                           \
  _Pragma("unroll") for (int mt_ = 0; mt_ < 2; ++mt_)                           \
  _Pragma("unroll") for (int nt_ = 0; nt_ < 2; ++nt_)                           \
    ACC[mt_][nt_] = __builtin_amdgcn_mfma_i32_32x32x32_i8(                      \
        A_[mt_][ks_], B_[nt_][ks_], ACC[mt_][nt_], 0, 0, 0);                    \
  __builtin_amdgcn_s_setprio(0);                                                \
  } while (0)

// Ledger (4 stage-items/iter): iter0/1 entry 0/4 out -> vmcnt(4) no-op,
// reads prologue-drained A0..3. Steady (i>=2): 8 out -> vmcnt(4) completes
// A(2i),A(2i+1). i==6: no stage -> 4 out at i==7 -> vmcnt(0). LGKM0_BAR
// is the WAR fence before ring-slot overwrite.
#define ITER(i, ACC, SB) do {                                                   \
    if ((i) == 7) WAIT0_BAR(); else WAITV4_BAR();                               \
    i32x4 a0[2][2], a1[2][2], b0[2][2], b1[2][2];                               \
    READ_A2(a0, 2 * (i));     READ_B2(b0, (2 * (i)) & 7, SB);                   \
    READ_A2(a1, 2 * (i) + 1); READ_B2(b1, (2 * (i) + 1) & 7, SB);               \
    MFMA8(ACC, a0, b0);                                                         \
    MFMA8(ACC, a1, b1);                                                         \
    LGKM0_BAR();                                                                \
    if ((i) < 6) { STAGE_A(2 * (i) + 4); STAGE_A(2 * (i) + 5); }                \
  } while (0)

__global__ __launch_bounds__(256, 2) void k_stft(const signed char* __restrict__ xe,
                                                 const signed char* __restrict__ xo,
                                                 const signed char* __restrict__ Aws,
                                                 const float2* __restrict__ tw,
                                                 float* __restrict__ out) {
  __shared__ __align__(16) signed char lds[67584];
  const int tid  = threadIdx.x;
  const int lane = tid & 63;
  const int wid  = tid >> 6;
  const int wr = wid >> 1;      // 0..1 (64 A-rows each)
  const int wc = wid & 1;       // 0..1 (64 frames each)
  const int lr = lane & 31;
  const int hi = lane >> 5;

  // XCD-bijective swizzle: 1920 = 8*240; mblk fastest (stream shared x4).
  const int bx = blockIdx.x;
  const int v = (bx & 7) * 240 + (bx >> 3);
  const int mblk = v & 3;
  const int nb = v >> 2;        // 0..479
  const int b  = nb / NBPB;
  const int f0 = (nb - b * NBPB) * BN;

  const signed char* se_src = xe + (size_t)b * SAMPH + (size_t)f0 * HOPH;
  const signed char* so_src = xo + (size_t)b * SAMPH + (size_t)f0 * HOPH;

  i32x16 accE[2][2], accO[2][2];
  #pragma unroll
  for (int i = 0; i < 2; ++i)
    #pragma unroll
    for (int j = 0; j < 2; ++j)
      #pragma unroll
      for (int e = 0; e < 16; ++e) { accE[i][j][e] = 0; accO[i][j][e] = 0; }

  STAGE_STREAM(se_src, SE);
  STAGE_STREAM(so_src, SO);
  STAGE_A(0); STAGE_A(1); STAGE_A(2); STAGE_A(3);
  WAIT0_BAR();

  ITER(0, accE, SE); ITER(1, accE, SE); ITER(2, accE, SE); ITER(3, accE, SE);
  ITER(4, accO, SO); ITER(5, accO, SO); ITER(6, accO, SO); ITER(7, accO, SO);

  // ---- epilogue: in-register radix-2 combine, twiddle from table ----
  // C/D: col = lane&31, row = (reg&3)+8*(reg>>2)+4*hi.
  // fq = mblk*64 + wr*32 + mt*16 + aa*4 + 2*hi + q  (<= 255).
  const int fbase = mblk * 64 + wr * 32;
  #pragma unroll
  for (int nt = 0; nt < 2; ++nt) {
    const int col = wc * 64 + nt * 32 + lr;
    const int tfi = f0 + col;
    if (tfi >= NFRAMES) continue;
    float* op = out + (size_t)b * ((size_t)NFREQ * NFRAMES) + tfi;
    #pragma unroll
    for (int mt = 0; mt < 2; ++mt) {
      i32x16 vE = accE[mt][nt];
      i32x16 vO = accO[mt][nt];
      #pragma unroll
      for (int aa = 0; aa < 4; ++aa)
        #pragma unroll
        for (int q = 0; q < 2; ++q) {
          const int fq = fbase + mt * 16 + aa * 4 + 2 * hi + q;
          float Ere = (float)vE[aa * 4 + 2 * q];
          float Eim = (float)vE[aa * 4 + 2 * q + 1];
          float Ore = (float)vO[aa * 4 + 2 * q];
          float Oim = (float)vO[aa * 4 + 2 * q + 1];
          if (fq == 0) {
            float sp = Ere + Ore, sm = Ere - Ore;
            op[0]                     = DEQ2 * sp * sp;
            op[(size_t)512 * NFRAMES] = DEQ2 * sm * sm;
            op[(size_t)256 * NFRAMES] = DEQ2 * (Eim * Eim + Oim * Oim);
          } else {
            float2 t = tw[fq];
            float Pre = t.x * Ore + t.y * Oim;
            float Pim = t.x * Oim - t.y * Ore;
            float ar = Ere + Pre, ai = Eim + Pim;
            float br = Ere - Pre, bi = Eim - Pim;
            op[(size_t)fq * NFRAMES]         = DEQ2 * (ar * ar + ai * ai);
            op[(size_t)(512 - fq) * NFRAMES] = DEQ2 * (br * br + bi * bi);
          }
        }
    }
  }
}

extern "C" void kernel_launch(void* const* d_in, const int* in_sizes, int n_in,
                              void* d_out, int out_size, void* d_ws, size_t ws_size,
                              hipStream_t stream) {
  const float* x      = (const float*)d_in[0];
  const float* narr   = (const float*)d_in[1];
  const float* w      = (const float*)d_in[2];
  const float* window = (const float*)d_in[3];
  float* out = (float*)d_out;

  signed char* xe  = (signed char*)d_ws;
  signed char* xo  = xe + (size_t)BATCH * SAMPH;
  signed char* Aws = xo + (size_t)BATCH * SAMPH;
  float2*      tw  = (float2*)(Aws + AWS_BYTES);
  if (ws_size < XH_BYTES + AWS_BYTES + TW_BYTES) return;  // ~15.9 MB

  k_prep<<<PREP_BLOCKS, 256, 0, stream>>>(x, narr, w, window, xe, xo, Aws, tw);
  k_stft<<<NWG, 256, 0, stream>>>(xe, xo, Aws, tw, out);
}